// Round 3
// baseline (788.425 us; speedup 1.0000x reference)
//
#include <hip/hip_runtime.h>
#include <math.h>

typedef _Float16 f16;
typedef f16 f16x8 __attribute__((ext_vector_type(8)));
typedef float f32x4 __attribute__((ext_vector_type(4)));

namespace {

constexpr int kB  = 32;
constexpr int kL  = 1024;
constexpr int kH  = 512;
constexpr int kP  = 336;
constexpr int kNL = 3;
constexpr int kNS = 32;

// async global->LDS, 16B per lane. LDS dest is wave-uniform base + lane*16.
__device__ __forceinline__ void llds16(const void* g, void* s) {
  __builtin_amdgcn_global_load_lds((const __attribute__((address_space(1))) void*)g,
                                   (__attribute__((address_space(3))) void*)s, 16, 0, 0);
}

// ---------------------------------------------------------------------------
// K0: SSM discretization params. r = exp(dt*A); Ct2 = 2*(C * expm1(dt*A)/A)
// ---------------------------------------------------------------------------
__global__ void ssm_params_kernel(const float* __restrict__ log_dt,
                                  const float* __restrict__ A_re,
                                  const float* __restrict__ A_im,
                                  const float* __restrict__ C_re,
                                  const float* __restrict__ C_im,
                                  float* __restrict__ prr, float* __restrict__ pri,
                                  float* __restrict__ pcr, float* __restrict__ pci) {
  int idx = blockIdx.x * blockDim.x + threadIdx.x;
  if (idx >= kNL * kH * kNS) return;
  int lh = idx / kNS;
  float dt = expf(log_dt[lh]);
  float ar = A_re[idx], ai = A_im[idx];
  float dr = dt * ar, di = dt * ai;
  float er = expf(dr);
  float c = cosf(di), s = sinf(di);
  float rr = er * c, ri = er * s;
  float sh = sinf(0.5f * di);
  float mr = expm1f(dr) * c - 2.f * sh * sh;
  float mi = ri;
  float inv = 1.f / (ar * ar + ai * ai);
  float qr = (mr * ar + mi * ai) * inv;
  float qi = (mi * ar - mr * ai) * inv;
  float cre = C_re[idx], cim = C_im[idx];
  prr[idx] = rr;
  pri[idx] = ri;
  pcr[idx] = 2.f * (cre * qr - cim * qi);
  pci[idx] = 2.f * (cre * qi + cim * qr);
}

// ---------------------------------------------------------------------------
// K1: fp32 -> fp16 convert (weights)
// ---------------------------------------------------------------------------
__global__ void f32_to_f16_kernel(const float* __restrict__ s, f16* __restrict__ d,
                                  int n) {
  int i = blockIdx.x * 256 + threadIdx.x;
  if (i < n) d[i] = (f16)s[i];
}

// ---------------------------------------------------------------------------
// K2: (B, L, E) fp32 -> (B, E, L) fp16 transpose
// ---------------------------------------------------------------------------
__global__ __launch_bounds__(256) void transpose_kernel(const float* __restrict__ x,
                                                        f16* __restrict__ u) {
  __shared__ float tile[32][33];
  int b = blockIdx.z;
  int l0 = blockIdx.x * 32, e0 = blockIdx.y * 32;
  int tx = threadIdx.x, ty = threadIdx.y;  // (32, 8)
#pragma unroll
  for (int k = 0; k < 4; k++)
    tile[ty + 8 * k][tx] = x[((size_t)b * kL + (size_t)(l0 + ty + 8 * k)) * kH + e0 + tx];
  __syncthreads();
#pragma unroll
  for (int k = 0; k < 4; k++)
    u[((size_t)b * kH + (size_t)(e0 + ty + 8 * k)) * kL + l0 + tx] =
        (f16)tile[tx][ty + 8 * k];
}

// ---------------------------------------------------------------------------
// K3: diagonal SSM recurrence + D-skip + GELU(tanh). fp16 in (B,H,L),
// fp16 out TRANSPOSED (B,L,H).
// 8 lanes per (b,h) row, 4 complex states per lane; reduction over n is
// 3 shfl_xor per step. 2048 waves -> 2 waves/SIMD for latency hiding.
// ---------------------------------------------------------------------------
__global__ __launch_bounds__(256) void s4_scan_kernel(
    const f16* __restrict__ uin, f16* __restrict__ yt,
    const float* __restrict__ prr, const float* __restrict__ pri,
    const float* __restrict__ pcr, const float* __restrict__ pci,
    const float* __restrict__ Dskip, int layer) {
  int tid = threadIdx.x;
  int g = (blockIdx.x << 5) + (tid >> 3);  // (b,h) row id, 32 rows per block
  int j = tid & 7;                         // lane within 8-lane group
  int h = g & (kH - 1);
  int b = g >> 9;

  float rr[4], ri[4], cr[4], ci[4], xr[4], xi[4];
  int base = ((layer * kH + h) << 5) + (j << 2);
#pragma unroll
  for (int s = 0; s < 4; s++) {
    rr[s] = prr[base + s];
    ri[s] = pri[base + s];
    cr[s] = pcr[base + s];
    ci[s] = pci[base + s];
    xr[s] = 0.f;
    xi[s] = 0.f;
  }
  float dsk = Dskip[layer * kH + h];

  const uint4* up = (const uint4*)(uin + ((size_t)g << 10));
  f16* ytb = yt + (size_t)b * kL * kH;

  union U8 {
    uint4 v;
    f16 e[8];
  };
  U8 cu, nu;
  cu.v = up[0];  // all 8 lanes of the group load the same 16B (broadcast, L1)

  for (int blk = 0; blk < 128; blk++) {  // 128 groups of 8 time steps
    if (blk < 127) nu.v = up[blk + 1];
    float keep = 0.f;
    float ukeep = 0.f;
#pragma unroll
    for (int i = 0; i < 8; i++) {
      float uu = (float)cu.e[i];
#pragma unroll
      for (int s = 0; s < 4; s++) {
        float nxr = fmaf(rr[s], xr[s], fmaf(-ri[s], xi[s], uu));
        float nxi = fmaf(rr[s], xi[s], ri[s] * xr[s]);
        xr[s] = nxr;
        xi[s] = nxi;
      }
      float t = 0.f;
#pragma unroll
      for (int s = 0; s < 4; s++) t = fmaf(cr[s], xr[s], fmaf(-ci[s], xi[s], t));
      t += __shfl_xor(t, 1);
      t += __shfl_xor(t, 2);
      t += __shfl_xor(t, 4);
      keep = (i == j) ? t : keep;    // lane j keeps step i == j
      ukeep = (i == j) ? uu : ukeep;
    }
    float y0 = fmaf(dsk, ukeep, keep);
    // GELU (tanh approx)
    float x3 = y0 * y0 * y0;
    float a = 0.7978845608028654f * fmaf(0.044715f, x3, y0);
    float aa = fminf(a, 15.f);
    float ex = __expf(2.f * aa);
    float th = 1.f - 2.f / (ex + 1.f);
    float val = 0.5f * y0 * (1.f + th);
    ytb[(size_t)(blk * 8 + j) * kH + h] = (f16)val;
    cu.v = nu.v;
  }
}

// ---------------------------------------------------------------------------
// K4: GLU GEMM via MFMA f16. Per block: A-tile = 128 Wo rows (h0..h0+63 of
// half1 and the matching half2 rows), B-tile = 128 l's, K=512 in BK=64 steps.
// LDS is fragment-ordered [subtile][lane][8 halves] -> conflict-free b128
// reads and global_load_lds-compatible (lane-contiguous).
// 4 waves, each 64x64 output; z1/z2 for the same h land in the same lane.
// ---------------------------------------------------------------------------
__global__ __launch_bounds__(256) void glu_mfma_kernel(
    const f16* __restrict__ yt,    // (B, L, H)
    const f16* __restrict__ wo,    // (2H, H) this layer
    const float* __restrict__ bo,  // (2H,)
    f16* __restrict__ uout) {      // (B, H, L)
  __shared__ __align__(16) f16 At[16][64][8];
  __shared__ __align__(16) f16 Bt[16][64][8];
  int tid = threadIdx.x;
  int lane = tid & 63, w = tid >> 6;
  int wm = w >> 1, wn = w & 1;
  int lr = lane & 15, lc = lane >> 4;
  int b = blockIdx.z, h0 = blockIdx.y * 64, l0 = blockIdx.x * 128;
  const f16* ytb = yt + (size_t)b * kL * kH;

  f32x4 acc[4][4] = {};

  const f16* gA[4];
  const f16* gB[4];
#pragma unroll
  for (int i = 0; i < 4; ++i) {
    int st = w * 4 + i, mt = st >> 1, ks = st & 1;
    int row = mt * 16 + lr;
    int hrow = (row < 64) ? (h0 + row) : (448 + h0 + row);  // 512 + h0 + (row-64)
    gA[i] = wo + (size_t)hrow * kH + ks * 32 + lc * 8;
    int lrow = l0 + mt * 16 + lr;
    gB[i] = ytb + (size_t)lrow * kH + ks * 32 + lc * 8;
  }

  for (int k0 = 0; k0 < kH; k0 += 64) {
#pragma unroll
    for (int i = 0; i < 4; ++i) {
      int st = w * 4 + i;
      llds16(gA[i] + k0, &At[st][0][0]);
      llds16(gB[i] + k0, &Bt[st][0][0]);
    }
    __syncthreads();
#pragma unroll
    for (int ks = 0; ks < 2; ++ks) {
      f16x8 av[4], bv[4];
      av[0] = *(const f16x8*)At[(2 * wm + 0) * 2 + ks][lane];
      av[1] = *(const f16x8*)At[(2 * wm + 1) * 2 + ks][lane];
      av[2] = *(const f16x8*)At[(2 * wm + 4) * 2 + ks][lane];
      av[3] = *(const f16x8*)At[(2 * wm + 5) * 2 + ks][lane];
#pragma unroll
      for (int nt = 0; nt < 4; ++nt)
        bv[nt] = *(const f16x8*)Bt[(wn * 4 + nt) * 2 + ks][lane];
#pragma unroll
      for (int i = 0; i < 4; ++i)
#pragma unroll
        for (int nt = 0; nt < 4; ++nt)
          acc[i][nt] =
              __builtin_amdgcn_mfma_f32_16x16x32_f16(av[i], bv[nt], acc[i][nt], 0, 0, 0);
    }
    __syncthreads();
  }

  // epilogue: C/D layout col=lane&15, row=(lane>>4)*4+reg
  int col = lane & 15, q = lane >> 4;
  f16* ub = uout + (size_t)b * kH * kL;
#pragma unroll
  for (int i = 0; i < 2; ++i) {
#pragma unroll
    for (int reg = 0; reg < 4; ++reg) {
      int h = h0 + wm * 32 + i * 16 + q * 4 + reg;
      float b1 = bo[h], b2 = bo[h + kH];
#pragma unroll
      for (int nt = 0; nt < 4; ++nt) {
        float z1 = acc[i][nt][reg] + b1;
        float z2 = acc[i + 2][nt][reg] + b2;
        float sg = 1.f / (1.f + __expf(-z2));
        ub[(size_t)h * kL + l0 + wn * 64 + nt * 16 + col] = (f16)(z1 * sg);
      }
    }
  }
}

// ---------------------------------------------------------------------------
// K5: final projection via MFMA f16. out[b,p,h] = sum_l W[p,l] X[b,h,l] + b[p].
// Block 128 p-rows x 128 h-cols, K = L = 1024.
// ---------------------------------------------------------------------------
__global__ __launch_bounds__(256) void final_mfma_kernel(
    const f16* __restrict__ x,     // (B, H, L)
    const f16* __restrict__ wout,  // (P, L)
    const float* __restrict__ bout,
    float* __restrict__ outp) {  // (B, P, H) fp32
  __shared__ __align__(16) f16 At[16][64][8];
  __shared__ __align__(16) f16 Bt[16][64][8];
  int tid = threadIdx.x;
  int lane = tid & 63, w = tid >> 6;
  int wm = w >> 1, wn = w & 1;
  int lr = lane & 15, lc = lane >> 4;
  int b = blockIdx.z, p0 = blockIdx.y * 128, h0 = blockIdx.x * 128;
  const f16* xb = x + (size_t)b * kH * kL;

  f32x4 acc[4][4] = {};

  const f16* gA[4];
  const f16* gB[4];
#pragma unroll
  for (int i = 0; i < 4; ++i) {
    int st = w * 4 + i, mt = st >> 1, ks = st & 1;
    int prow = p0 + mt * 16 + lr;
    if (prow > kP - 1) prow = kP - 1;  // clamp; masked at store
    gA[i] = wout + (size_t)prow * kL + ks * 32 + lc * 8;
    int hrow = h0 + mt * 16 + lr;
    gB[i] = xb + (size_t)hrow * kL + ks * 32 + lc * 8;
  }

  for (int k0 = 0; k0 < kL; k0 += 64) {
#pragma unroll
    for (int i = 0; i < 4; ++i) {
      int st = w * 4 + i;
      llds16(gA[i] + k0, &At[st][0][0]);
      llds16(gB[i] + k0, &Bt[st][0][0]);
    }
    __syncthreads();
#pragma unroll
    for (int ks = 0; ks < 2; ++ks) {
      f16x8 av[4], bv[4];
#pragma unroll
      for (int i = 0; i < 4; ++i)
        av[i] = *(const f16x8*)At[(wm * 4 + i) * 2 + ks][lane];
#pragma unroll
      for (int nt = 0; nt < 4; ++nt)
        bv[nt] = *(const f16x8*)Bt[(wn * 4 + nt) * 2 + ks][lane];
#pragma unroll
      for (int i = 0; i < 4; ++i)
#pragma unroll
        for (int nt = 0; nt < 4; ++nt)
          acc[i][nt] =
              __builtin_amdgcn_mfma_f32_16x16x32_f16(av[i], bv[nt], acc[i][nt], 0, 0, 0);
    }
    __syncthreads();
  }

  int col = lane & 15, q = lane >> 4;
  float* ob = outp + (size_t)b * kP * kH;
#pragma unroll
  for (int i = 0; i < 4; ++i) {
#pragma unroll
    for (int reg = 0; reg < 4; ++reg) {
      int p = p0 + wm * 64 + i * 16 + q * 4 + reg;
      if (p < kP) {
        float bv2 = bout[p];
#pragma unroll
        for (int nt = 0; nt < 4; ++nt)
          ob[(size_t)p * kH + h0 + wn * 64 + nt * 16 + col] = acc[i][nt][reg] + bv2;
      }
    }
  }
}

}  // namespace

extern "C" void kernel_launch(void* const* d_in, const int* in_sizes, int n_in,
                              void* d_out, int out_size, void* d_ws, size_t ws_size,
                              hipStream_t stream) {
  const float* x_enc  = (const float*)d_in[0];
  const float* log_dt = (const float*)d_in[4];
  const float* A_re   = (const float*)d_in[5];
  const float* A_im   = (const float*)d_in[6];
  const float* C_re   = (const float*)d_in[7];
  const float* C_im   = (const float*)d_in[8];
  const float* Dskip  = (const float*)d_in[9];
  const float* Wo     = (const float*)d_in[10];
  const float* bo     = (const float*)d_in[11];
  const float* W_out  = (const float*)d_in[12];
  const float* b_out  = (const float*)d_in[13];
  float* out = (float*)d_out;

  char* wsb = (char*)d_ws;
  f16* u16    = (f16*)(wsb);                  // 32 MB  (B,H,L)
  f16* yt16   = (f16*)(wsb + 33554432);       // 32 MB  (B,L,H)
  f16* wo16   = (f16*)(wsb + 67108864);       // 3 MB   (NL,2H,H)
  f16* wout16 = (f16*)(wsb + 70254592);       // 672 KB (P,L)
  float* prr  = (float*)(wsb + 70942720);
  float* pri  = prr + kNL * kH * kNS;
  float* pcr  = pri + kNL * kH * kNS;
  float* pci  = pcr + kNL * kH * kNS;

  const int nwo = kNL * 2 * kH * kH;  // 1,572,864
  const int nwp = kP * kL;            // 344,064
  f32_to_f16_kernel<<<(nwo + 255) / 256, 256, 0, stream>>>(Wo, wo16, nwo);
  f32_to_f16_kernel<<<(nwp + 255) / 256, 256, 0, stream>>>(W_out, wout16, nwp);

  ssm_params_kernel<<<(kNL * kH * kNS + 255) / 256, 256, 0, stream>>>(
      log_dt, A_re, A_im, C_re, C_im, prr, pri, pcr, pci);

  transpose_kernel<<<dim3(kL / 32, kH / 32, kB), dim3(32, 8), 0, stream>>>(x_enc, u16);

  for (int layer = 0; layer < kNL; layer++) {
    s4_scan_kernel<<<kB * kH / 32, 256, 0, stream>>>(u16, yt16, prr, pri, pcr, pci,
                                                     Dskip, layer);
    glu_mfma_kernel<<<dim3(kL / 128, kH / 64, kB), 256, 0, stream>>>(
        yt16, wo16 + (size_t)layer * 2 * kH * kH, bo + (size_t)layer * 2 * kH, u16);
  }

  final_mfma_kernel<<<dim3(kH / 128, 3, kB), 256, 0, stream>>>(u16, wout16, b_out, out);
}

// Round 4
// 723.916 us; speedup vs baseline: 1.0891x; 1.0891x over previous
//
#include <hip/hip_runtime.h>
#include <math.h>

typedef _Float16 f16;
typedef f16 f16x8 __attribute__((ext_vector_type(8)));
typedef float f32x4 __attribute__((ext_vector_type(4)));

namespace {

constexpr int kB  = 32;
constexpr int kL  = 1024;
constexpr int kH  = 512;
constexpr int kP  = 336;
constexpr int kNL = 3;
constexpr int kNS = 32;

// async global->LDS, 16B per lane. LDS dest is wave-uniform base + lane*16.
__device__ __forceinline__ void llds16(const void* g, void* s) {
  __builtin_amdgcn_global_load_lds((const __attribute__((address_space(1))) void*)g,
                                   (__attribute__((address_space(3))) void*)s, 16, 0, 0);
}

// ---------------------------------------------------------------------------
// K0: SSM discretization params. r = exp(dt*A); Ct2 = 2*(C * expm1(dt*A)/A)
// ---------------------------------------------------------------------------
__global__ void ssm_params_kernel(const float* __restrict__ log_dt,
                                  const float* __restrict__ A_re,
                                  const float* __restrict__ A_im,
                                  const float* __restrict__ C_re,
                                  const float* __restrict__ C_im,
                                  float* __restrict__ prr, float* __restrict__ pri,
                                  float* __restrict__ pcr, float* __restrict__ pci) {
  int idx = blockIdx.x * blockDim.x + threadIdx.x;
  if (idx >= kNL * kH * kNS) return;
  int lh = idx / kNS;
  float dt = expf(log_dt[lh]);
  float ar = A_re[idx], ai = A_im[idx];
  float dr = dt * ar, di = dt * ai;
  float er = expf(dr);
  float c = cosf(di), s = sinf(di);
  float rr = er * c, ri = er * s;
  float sh = sinf(0.5f * di);
  float mr = expm1f(dr) * c - 2.f * sh * sh;
  float mi = ri;
  float inv = 1.f / (ar * ar + ai * ai);
  float qr = (mr * ar + mi * ai) * inv;
  float qi = (mi * ar - mr * ai) * inv;
  float cre = C_re[idx], cim = C_im[idx];
  prr[idx] = rr;
  pri[idx] = ri;
  pcr[idx] = 2.f * (cre * qr - cim * qi);
  pci[idx] = 2.f * (cre * qi + cim * qr);
}

// ---------------------------------------------------------------------------
// K1: fp32 -> fp16 convert (weights)
// ---------------------------------------------------------------------------
__global__ void f32_to_f16_kernel(const float* __restrict__ s, f16* __restrict__ d,
                                  int n) {
  int i = blockIdx.x * 256 + threadIdx.x;
  if (i < n) d[i] = (f16)s[i];
}

// ---------------------------------------------------------------------------
// K2: (B, L, E) fp32 -> (B, E, L) fp16 transpose
// ---------------------------------------------------------------------------
__global__ __launch_bounds__(256) void transpose_kernel(const float* __restrict__ x,
                                                        f16* __restrict__ u) {
  __shared__ float tile[32][33];
  int b = blockIdx.z;
  int l0 = blockIdx.x * 32, e0 = blockIdx.y * 32;
  int tx = threadIdx.x, ty = threadIdx.y;  // (32, 8)
#pragma unroll
  for (int k = 0; k < 4; k++)
    tile[ty + 8 * k][tx] = x[((size_t)b * kL + (size_t)(l0 + ty + 8 * k)) * kH + e0 + tx];
  __syncthreads();
#pragma unroll
  for (int k = 0; k < 4; k++)
    u[((size_t)b * kH + (size_t)(e0 + ty + 8 * k)) * kL + l0 + tx] =
        (f16)tile[tx][ty + 8 * k];
}

// ---------------------------------------------------------------------------
// K3: diagonal SSM recurrence + D-skip + GELU(tanh). fp16 in (B,H,L),
// fp16 out TRANSPOSED (B,L,H).
// 8 lanes per (b,h) row, 4 complex states per lane. 16 steps per inner block:
// per-step partials kept in registers (no shuffles), then ONE 3-stage
// recursive-halving exchange per block (independent shuffles within a stage).
// Lane j ends owning fully-reduced steps 2j and 2j+1.
// D-skip folded as (Dskip/8)*u added by all 8 lanes pre-reduction.
// ---------------------------------------------------------------------------
__global__ __launch_bounds__(256) void s4_scan_kernel(
    const f16* __restrict__ uin, f16* __restrict__ yt,
    const float* __restrict__ prr, const float* __restrict__ pri,
    const float* __restrict__ pcr, const float* __restrict__ pci,
    const float* __restrict__ Dskip, int layer) {
  int tid = threadIdx.x;
  int g = (blockIdx.x << 5) + (tid >> 3);  // (b,h) row id, 32 rows per block
  int j = tid & 7;                         // lane within 8-lane group
  int h = g & (kH - 1);
  int b = g >> 9;

  float rr[4], ri[4], cr[4], ci[4], xr[4], xi[4];
  int base = ((layer * kH + h) << 5) + (j << 2);
#pragma unroll
  for (int s = 0; s < 4; s++) {
    rr[s] = prr[base + s];
    ri[s] = pri[base + s];
    cr[s] = pcr[base + s];
    ci[s] = pci[base + s];
    xr[s] = 0.f;
    xi[s] = 0.f;
  }
  float dsk8 = Dskip[layer * kH + h] * 0.125f;

  const uint4* up = (const uint4*)(uin + ((size_t)g << 10));
  f16* ytb = yt + (size_t)b * kL * kH + h;

  union U16 {
    uint4 v[2];
    f16 e[16];
  };
  U16 cu, nu;
  cu.v[0] = up[0];  // all 8 lanes of the group load the same 16B (broadcast)
  cu.v[1] = up[1];

  bool k4 = (j & 4) != 0, k2 = (j & 2) != 0, k1 = (j & 1) != 0;

  for (int blk = 0; blk < 64; blk++) {  // 64 blocks of 16 time steps
    if (blk < 63) {
      nu.v[0] = up[2 * blk + 2];
      nu.v[1] = up[2 * blk + 3];
    }
    float p[16];
#pragma unroll
    for (int i = 0; i < 16; i++) {
      float uu = (float)cu.e[i];
#pragma unroll
      for (int s = 0; s < 4; s++) {
        float nxr = fmaf(rr[s], xr[s], fmaf(-ri[s], xi[s], uu));
        float nxi = fmaf(rr[s], xi[s], ri[s] * xr[s]);
        xr[s] = nxr;
        xi[s] = nxi;
      }
      float t0 = 0.f, t1 = 0.f;
      t0 = fmaf(cr[0], xr[0], fmaf(-ci[0], xi[0], t0));
      t0 = fmaf(cr[1], xr[1], fmaf(-ci[1], xi[1], t0));
      t1 = fmaf(cr[2], xr[2], fmaf(-ci[2], xi[2], t1));
      t1 = fmaf(cr[3], xr[3], fmaf(-ci[3], xi[3], t1));
      p[i] = fmaf(dsk8, uu, t0 + t1);  // D-skip/8 per lane; sums to D-skip
    }
    // ---- recursive-halving reduce: stage xor4 (8 regs), xor2 (4), xor1 (2)
#pragma unroll
    for (int k = 0; k < 8; k++) {
      float send = k4 ? p[k] : p[k + 8];
      float recv = __shfl_xor(send, 4);
      float keep = k4 ? p[k + 8] : p[k];
      p[k] = keep + recv;
    }
#pragma unroll
    for (int k = 0; k < 4; k++) {
      float send = k2 ? p[k] : p[k + 4];
      float recv = __shfl_xor(send, 2);
      float keep = k2 ? p[k + 4] : p[k];
      p[k] = keep + recv;
    }
#pragma unroll
    for (int k = 0; k < 2; k++) {
      float send = k1 ? p[k] : p[k + 2];
      float recv = __shfl_xor(send, 1);
      float keep = k1 ? p[k + 2] : p[k];
      p[k] = keep + recv;
    }
    // lane j owns steps 2j and 2j+1 of this 16-step block
#pragma unroll
    for (int t = 0; t < 2; t++) {
      float y0 = p[t];
      float x3 = y0 * y0 * y0;
      float a = 0.7978845608028654f * fmaf(0.044715f, x3, y0);
      float aa = fminf(a, 15.f);
      float ex = __expf(2.f * aa);
      float th = 1.f - 2.f / (ex + 1.f);
      float val = 0.5f * y0 * (1.f + th);
      ytb[(size_t)(blk * 16 + 2 * j + t) * kH] = (f16)val;
    }
    cu.v[0] = nu.v[0];
    cu.v[1] = nu.v[1];
  }
}

// ---------------------------------------------------------------------------
// K4: GLU GEMM via MFMA f16. Per block: A-tile = 128 Wo rows (h0..h0+63 of
// half1 and the matching half2 rows), B-tile = 128 l's, K=512 in BK=64 steps.
// LDS is fragment-ordered [subtile][lane][8 halves] -> conflict-free b128
// reads and global_load_lds-compatible (lane-contiguous).
// 4 waves, each 64x64 output; z1/z2 for the same h land in the same lane.
// ---------------------------------------------------------------------------
__global__ __launch_bounds__(256) void glu_mfma_kernel(
    const f16* __restrict__ yt,    // (B, L, H)
    const f16* __restrict__ wo,    // (2H, H) this layer
    const float* __restrict__ bo,  // (2H,)
    f16* __restrict__ uout) {      // (B, H, L)
  __shared__ __align__(16) f16 At[16][64][8];
  __shared__ __align__(16) f16 Bt[16][64][8];
  int tid = threadIdx.x;
  int lane = tid & 63, w = tid >> 6;
  int wm = w >> 1, wn = w & 1;
  int lr = lane & 15, lc = lane >> 4;
  int b = blockIdx.z, h0 = blockIdx.y * 64, l0 = blockIdx.x * 128;
  const f16* ytb = yt + (size_t)b * kL * kH;

  f32x4 acc[4][4] = {};

  const f16* gA[4];
  const f16* gB[4];
#pragma unroll
  for (int i = 0; i < 4; ++i) {
    int st = w * 4 + i, mt = st >> 1, ks = st & 1;
    int row = mt * 16 + lr;
    int hrow = (row < 64) ? (h0 + row) : (448 + h0 + row);  // 512 + h0 + (row-64)
    gA[i] = wo + (size_t)hrow * kH + ks * 32 + lc * 8;
    int lrow = l0 + mt * 16 + lr;
    gB[i] = ytb + (size_t)lrow * kH + ks * 32 + lc * 8;
  }

  for (int k0 = 0; k0 < kH; k0 += 64) {
#pragma unroll
    for (int i = 0; i < 4; ++i) {
      int st = w * 4 + i;
      llds16(gA[i] + k0, &At[st][0][0]);
      llds16(gB[i] + k0, &Bt[st][0][0]);
    }
    __syncthreads();
#pragma unroll
    for (int ks = 0; ks < 2; ++ks) {
      f16x8 av[4], bv[4];
      av[0] = *(const f16x8*)At[(2 * wm + 0) * 2 + ks][lane];
      av[1] = *(const f16x8*)At[(2 * wm + 1) * 2 + ks][lane];
      av[2] = *(const f16x8*)At[(2 * wm + 4) * 2 + ks][lane];
      av[3] = *(const f16x8*)At[(2 * wm + 5) * 2 + ks][lane];
#pragma unroll
      for (int nt = 0; nt < 4; ++nt)
        bv[nt] = *(const f16x8*)Bt[(wn * 4 + nt) * 2 + ks][lane];
#pragma unroll
      for (int i = 0; i < 4; ++i)
#pragma unroll
        for (int nt = 0; nt < 4; ++nt)
          acc[i][nt] =
              __builtin_amdgcn_mfma_f32_16x16x32_f16(av[i], bv[nt], acc[i][nt], 0, 0, 0);
    }
    __syncthreads();
  }

  // epilogue: C/D layout col=lane&15, row=(lane>>4)*4+reg
  int col = lane & 15, q = lane >> 4;
  f16* ub = uout + (size_t)b * kH * kL;
#pragma unroll
  for (int i = 0; i < 2; ++i) {
#pragma unroll
    for (int reg = 0; reg < 4; ++reg) {
      int h = h0 + wm * 32 + i * 16 + q * 4 + reg;
      float b1 = bo[h], b2 = bo[h + kH];
#pragma unroll
      for (int nt = 0; nt < 4; ++nt) {
        float z1 = acc[i][nt][reg] + b1;
        float z2 = acc[i + 2][nt][reg] + b2;
        float sg = 1.f / (1.f + __expf(-z2));
        ub[(size_t)h * kL + l0 + wn * 64 + nt * 16 + col] = (f16)(z1 * sg);
      }
    }
  }
}

// ---------------------------------------------------------------------------
// K5: final projection via MFMA f16. out[b,p,h] = sum_l W[p,l] X[b,h,l] + b[p].
// Block 128 p-rows x 128 h-cols, K = L = 1024.
// ---------------------------------------------------------------------------
__global__ __launch_bounds__(256) void final_mfma_kernel(
    const f16* __restrict__ x,     // (B, H, L)
    const f16* __restrict__ wout,  // (P, L)
    const float* __restrict__ bout,
    float* __restrict__ outp) {  // (B, P, H) fp32
  __shared__ __align__(16) f16 At[16][64][8];
  __shared__ __align__(16) f16 Bt[16][64][8];
  int tid = threadIdx.x;
  int lane = tid & 63, w = tid >> 6;
  int wm = w >> 1, wn = w & 1;
  int lr = lane & 15, lc = lane >> 4;
  int b = blockIdx.z, p0 = blockIdx.y * 128, h0 = blockIdx.x * 128;
  const f16* xb = x + (size_t)b * kH * kL;

  f32x4 acc[4][4] = {};

  const f16* gA[4];
  const f16* gB[4];
#pragma unroll
  for (int i = 0; i < 4; ++i) {
    int st = w * 4 + i, mt = st >> 1, ks = st & 1;
    int prow = p0 + mt * 16 + lr;
    if (prow > kP - 1) prow = kP - 1;  // clamp; masked at store
    gA[i] = wout + (size_t)prow * kL + ks * 32 + lc * 8;
    int hrow = h0 + mt * 16 + lr;
    gB[i] = xb + (size_t)hrow * kL + ks * 32 + lc * 8;
  }

  for (int k0 = 0; k0 < kL; k0 += 64) {
#pragma unroll
    for (int i = 0; i < 4; ++i) {
      int st = w * 4 + i;
      llds16(gA[i] + k0, &At[st][0][0]);
      llds16(gB[i] + k0, &Bt[st][0][0]);
    }
    __syncthreads();
#pragma unroll
    for (int ks = 0; ks < 2; ++ks) {
      f16x8 av[4], bv[4];
#pragma unroll
      for (int i = 0; i < 4; ++i)
        av[i] = *(const f16x8*)At[(wm * 4 + i) * 2 + ks][lane];
#pragma unroll
      for (int nt = 0; nt < 4; ++nt)
        bv[nt] = *(const f16x8*)Bt[(wn * 4 + nt) * 2 + ks][lane];
#pragma unroll
      for (int i = 0; i < 4; ++i)
#pragma unroll
        for (int nt = 0; nt < 4; ++nt)
          acc[i][nt] =
              __builtin_amdgcn_mfma_f32_16x16x32_f16(av[i], bv[nt], acc[i][nt], 0, 0, 0);
    }
    __syncthreads();
  }

  int col = lane & 15, q = lane >> 4;
  float* ob = outp + (size_t)b * kP * kH;
#pragma unroll
  for (int i = 0; i < 4; ++i) {
#pragma unroll
    for (int reg = 0; reg < 4; ++reg) {
      int p = p0 + wm * 64 + i * 16 + q * 4 + reg;
      if (p < kP) {
        float bv2 = bout[p];
#pragma unroll
        for (int nt = 0; nt < 4; ++nt)
          ob[(size_t)p * kH + h0 + wn * 64 + nt * 16 + col] = acc[i][nt][reg] + bv2;
      }
    }
  }
}

}  // namespace

extern "C" void kernel_launch(void* const* d_in, const int* in_sizes, int n_in,
                              void* d_out, int out_size, void* d_ws, size_t ws_size,
                              hipStream_t stream) {
  const float* x_enc  = (const float*)d_in[0];
  const float* log_dt = (const float*)d_in[4];
  const float* A_re   = (const float*)d_in[5];
  const float* A_im   = (const float*)d_in[6];
  const float* C_re   = (const float*)d_in[7];
  const float* C_im   = (const float*)d_in[8];
  const float* Dskip  = (const float*)d_in[9];
  const float* Wo     = (const float*)d_in[10];
  const float* bo     = (const float*)d_in[11];
  const float* W_out  = (const float*)d_in[12];
  const float* b_out  = (const float*)d_in[13];
  float* out = (float*)d_out;

  char* wsb = (char*)d_ws;
  f16* u16    = (f16*)(wsb);                  // 32 MB  (B,H,L)
  f16* yt16   = (f16*)(wsb + 33554432);       // 32 MB  (B,L,H)
  f16* wo16   = (f16*)(wsb + 67108864);       // 3 MB   (NL,2H,H)
  f16* wout16 = (f16*)(wsb + 70254592);       // 672 KB (P,L)
  float* prr  = (float*)(wsb + 70942720);
  float* pri  = prr + kNL * kH * kNS;
  float* pcr  = pri + kNL * kH * kNS;
  float* pci  = pcr + kNL * kH * kNS;

  const int nwo = kNL * 2 * kH * kH;  // 1,572,864
  const int nwp = kP * kL;            // 344,064
  f32_to_f16_kernel<<<(nwo + 255) / 256, 256, 0, stream>>>(Wo, wo16, nwo);
  f32_to_f16_kernel<<<(nwp + 255) / 256, 256, 0, stream>>>(W_out, wout16, nwp);

  ssm_params_kernel<<<(kNL * kH * kNS + 255) / 256, 256, 0, stream>>>(
      log_dt, A_re, A_im, C_re, C_im, prr, pri, pcr, pci);

  transpose_kernel<<<dim3(kL / 32, kH / 32, kB), dim3(32, 8), 0, stream>>>(x_enc, u16);

  for (int layer = 0; layer < kNL; layer++) {
    s4_scan_kernel<<<kB * kH / 32, 256, 0, stream>>>(u16, yt16, prr, pri, pcr, pci,
                                                     Dskip, layer);
    glu_mfma_kernel<<<dim3(kL / 128, kH / 64, kB), 256, 0, stream>>>(
        yt16, wo16 + (size_t)layer * 2 * kH * kH, bo + (size_t)layer * 2 * kH, u16);
  }

  final_mfma_kernel<<<dim3(kH / 128, 3, kB), 256, 0, stream>>>(u16, wout16, b_out, out);
}

// Round 5
// 713.612 us; speedup vs baseline: 1.1048x; 1.0144x over previous
//
#include <hip/hip_runtime.h>
#include <math.h>

typedef _Float16 f16;
typedef f16 f16x8 __attribute__((ext_vector_type(8)));
typedef float f32x4 __attribute__((ext_vector_type(4)));
typedef float f32x2 __attribute__((ext_vector_type(2)));

namespace {

constexpr int kB  = 32;
constexpr int kL  = 1024;
constexpr int kH  = 512;
constexpr int kP  = 336;
constexpr int kNL = 3;
constexpr int kNS = 32;

// async global->LDS, 16B per lane. LDS dest is wave-uniform base + lane*16.
__device__ __forceinline__ void llds16(const void* g, void* s) {
  __builtin_amdgcn_global_load_lds((const __attribute__((address_space(1))) void*)g,
                                   (__attribute__((address_space(3))) void*)s, 16, 0, 0);
}

// packed fp32 math (VOP3P, full-rate dual fp32 on CDNA3+)
__device__ __forceinline__ f32x2 pk_fma(f32x2 a, f32x2 b, f32x2 c) {
  f32x2 d;
  asm("v_pk_fma_f32 %0, %1, %2, %3" : "=v"(d) : "v"(a), "v"(b), "v"(c));
  return d;
}
__device__ __forceinline__ f32x2 pk_mul(f32x2 a, f32x2 b) {
  f32x2 d;
  asm("v_pk_mul_f32 %0, %1, %2" : "=v"(d) : "v"(a), "v"(b));
  return d;
}

// ---------------------------------------------------------------------------
// K0: SSM discretization params. r = exp(dt*A); Ct2 = 2*(C * expm1(dt*A)/A)
// ---------------------------------------------------------------------------
__global__ void ssm_params_kernel(const float* __restrict__ log_dt,
                                  const float* __restrict__ A_re,
                                  const float* __restrict__ A_im,
                                  const float* __restrict__ C_re,
                                  const float* __restrict__ C_im,
                                  float* __restrict__ prr, float* __restrict__ pri,
                                  float* __restrict__ pcr, float* __restrict__ pci) {
  int idx = blockIdx.x * blockDim.x + threadIdx.x;
  if (idx >= kNL * kH * kNS) return;
  int lh = idx / kNS;
  float dt = expf(log_dt[lh]);
  float ar = A_re[idx], ai = A_im[idx];
  float dr = dt * ar, di = dt * ai;
  float er = expf(dr);
  float c = cosf(di), s = sinf(di);
  float rr = er * c, ri = er * s;
  float sh = sinf(0.5f * di);
  float mr = expm1f(dr) * c - 2.f * sh * sh;
  float mi = ri;
  float inv = 1.f / (ar * ar + ai * ai);
  float qr = (mr * ar + mi * ai) * inv;
  float qi = (mi * ar - mr * ai) * inv;
  float cre = C_re[idx], cim = C_im[idx];
  prr[idx] = rr;
  pri[idx] = ri;
  pcr[idx] = 2.f * (cre * qr - cim * qi);
  pci[idx] = 2.f * (cre * qi + cim * qr);
}

// ---------------------------------------------------------------------------
// K1: fp32 -> fp16 convert (weights)
// ---------------------------------------------------------------------------
__global__ void f32_to_f16_kernel(const float* __restrict__ s, f16* __restrict__ d,
                                  int n) {
  int i = blockIdx.x * 256 + threadIdx.x;
  if (i < n) d[i] = (f16)s[i];
}

// ---------------------------------------------------------------------------
// K2: (B, L, E) fp32 -> (B, E, L) fp16 transpose
// ---------------------------------------------------------------------------
__global__ __launch_bounds__(256) void transpose_kernel(const float* __restrict__ x,
                                                        f16* __restrict__ u) {
  __shared__ float tile[32][33];
  int b = blockIdx.z;
  int l0 = blockIdx.x * 32, e0 = blockIdx.y * 32;
  int tx = threadIdx.x, ty = threadIdx.y;  // (32, 8)
#pragma unroll
  for (int k = 0; k < 4; k++)
    tile[ty + 8 * k][tx] = x[((size_t)b * kL + (size_t)(l0 + ty + 8 * k)) * kH + e0 + tx];
  __syncthreads();
#pragma unroll
  for (int k = 0; k < 4; k++)
    u[((size_t)b * kH + (size_t)(e0 + ty + 8 * k)) * kL + l0 + tx] =
        (f16)tile[tx][ty + 8 * k];
}

// ---------------------------------------------------------------------------
// K3: diagonal SSM recurrence + D-skip + GELU(tanh). fp16 in (B,H,L),
// fp16 out TRANSPOSED (B,L,H).
// 8 lanes per (b,h) row, 4 complex states per lane packed as 2 f32x2 pairs
// (v_pk_fma_f32 halves the VALU op count of the recurrence core).
// 16 steps per inner block: register partials, then one 3-stage
// recursive-halving exchange; lane j ends owning steps 2j, 2j+1.
// D-skip folded as (Dskip/8)*u added by all 8 lanes pre-reduction.
// ---------------------------------------------------------------------------
__global__ __launch_bounds__(256) void s4_scan_kernel(
    const f16* __restrict__ uin, f16* __restrict__ yt,
    const float* __restrict__ prr, const float* __restrict__ pri,
    const float* __restrict__ pcr, const float* __restrict__ pci,
    const float* __restrict__ Dskip, int layer) {
  int tid = threadIdx.x;
  int g = (blockIdx.x << 5) + (tid >> 3);  // (b,h) row id, 32 rows per block
  int j = tid & 7;                         // lane within 8-lane group
  int h = g & (kH - 1);
  int b = g >> 9;

  f32x2 rr2[2], ri2[2], nri2[2], cr2[2], nci2[2], xr2[2], xi2[2];
  int base = ((layer * kH + h) << 5) + (j << 2);
#pragma unroll
  for (int k = 0; k < 2; k++) {
    rr2[k]  = f32x2{prr[base + 2 * k], prr[base + 2 * k + 1]};
    ri2[k]  = f32x2{pri[base + 2 * k], pri[base + 2 * k + 1]};
    nri2[k] = f32x2{-ri2[k].x, -ri2[k].y};
    cr2[k]  = f32x2{pcr[base + 2 * k], pcr[base + 2 * k + 1]};
    nci2[k] = f32x2{-pci[base + 2 * k], -pci[base + 2 * k + 1]};
    xr2[k]  = f32x2{0.f, 0.f};
    xi2[k]  = f32x2{0.f, 0.f};
  }
  float dsk8 = Dskip[layer * kH + h] * 0.125f;

  const uint4* up = (const uint4*)(uin + ((size_t)g << 10));
  f16* ytb = yt + (size_t)b * kL * kH + h;

  union U16 {
    uint4 v[2];
    f16 e[16];
  };
  U16 cu, nu;
  cu.v[0] = up[0];  // all 8 lanes of the group load the same 16B (broadcast)
  cu.v[1] = up[1];

  bool k4 = (j & 4) != 0, k2 = (j & 2) != 0, k1 = (j & 1) != 0;

  for (int blk = 0; blk < 64; blk++) {  // 64 blocks of 16 time steps
    if (blk < 63) {
      nu.v[0] = up[2 * blk + 2];
      nu.v[1] = up[2 * blk + 3];
    }
    float p[16];
#pragma unroll
    for (int i = 0; i < 16; i++) {
      float uu = (float)cu.e[i];
      f32x2 uu2 = {uu, uu};
#pragma unroll
      for (int k = 0; k < 2; k++) {
        f32x2 t  = pk_fma(nri2[k], xi2[k], uu2);       // -ri*xi + u
        f32x2 nr = pk_fma(rr2[k], xr2[k], t);          // rr*xr - ri*xi + u
        f32x2 ti = pk_mul(ri2[k], xr2[k]);             // ri*xr
        f32x2 ni = pk_fma(rr2[k], xi2[k], ti);         // rr*xi + ri*xr
        xr2[k] = nr;
        xi2[k] = ni;
      }
      f32x2 t2 = pk_mul(cr2[0], xr2[0]);
      t2 = pk_fma(cr2[1], xr2[1], t2);
      t2 = pk_fma(nci2[0], xi2[0], t2);
      t2 = pk_fma(nci2[1], xi2[1], t2);
      p[i] = fmaf(dsk8, uu, t2.x + t2.y);  // D-skip/8 per lane; sums to D-skip
    }
    // ---- recursive-halving reduce: stage xor4 (8 regs), xor2 (4), xor1 (2)
#pragma unroll
    for (int k = 0; k < 8; k++) {
      float send = k4 ? p[k] : p[k + 8];
      float recv = __shfl_xor(send, 4);
      float keep = k4 ? p[k + 8] : p[k];
      p[k] = keep + recv;
    }
#pragma unroll
    for (int k = 0; k < 4; k++) {
      float send = k2 ? p[k] : p[k + 4];
      float recv = __shfl_xor(send, 2);
      float keep = k2 ? p[k + 4] : p[k];
      p[k] = keep + recv;
    }
#pragma unroll
    for (int k = 0; k < 2; k++) {
      float send = k1 ? p[k] : p[k + 2];
      float recv = __shfl_xor(send, 1);
      float keep = k1 ? p[k + 2] : p[k];
      p[k] = keep + recv;
    }
    // lane j owns steps 2j and 2j+1 of this 16-step block
#pragma unroll
    for (int t = 0; t < 2; t++) {
      float y0 = p[t];
      float x3 = y0 * y0 * y0;
      float a = 0.7978845608028654f * fmaf(0.044715f, x3, y0);
      float aa = fminf(a, 15.f);
      float ex = __expf(2.f * aa);
      float th = 1.f - 2.f / (ex + 1.f);
      float val = 0.5f * y0 * (1.f + th);
      ytb[(size_t)(blk * 16 + 2 * j + t) * kH] = (f16)val;
    }
    cu.v[0] = nu.v[0];
    cu.v[1] = nu.v[1];
  }
}

// ---------------------------------------------------------------------------
// K4: GLU GEMM via MFMA f16. Per block: A-tile = 128 Wo rows (h0..h0+63 of
// half1 and the matching half2 rows), B-tile = 128 l's, K=512 in BK=64 steps.
// LDS is fragment-ordered [subtile][lane][8 halves] -> conflict-free b128
// reads and global_load_lds-compatible (lane-contiguous).
// 4 waves, each 64x64 output; z1/z2 for the same h land in the same lane.
// ---------------------------------------------------------------------------
__global__ __launch_bounds__(256) void glu_mfma_kernel(
    const f16* __restrict__ yt,    // (B, L, H)
    const f16* __restrict__ wo,    // (2H, H) this layer
    const float* __restrict__ bo,  // (2H,)
    f16* __restrict__ uout) {      // (B, H, L)
  __shared__ __align__(16) f16 At[16][64][8];
  __shared__ __align__(16) f16 Bt[16][64][8];
  int tid = threadIdx.x;
  int lane = tid & 63, w = tid >> 6;
  int wm = w >> 1, wn = w & 1;
  int lr = lane & 15, lc = lane >> 4;
  int b = blockIdx.z, h0 = blockIdx.y * 64, l0 = blockIdx.x * 128;
  const f16* ytb = yt + (size_t)b * kL * kH;

  f32x4 acc[4][4] = {};

  const f16* gA[4];
  const f16* gB[4];
#pragma unroll
  for (int i = 0; i < 4; ++i) {
    int st = w * 4 + i, mt = st >> 1, ks = st & 1;
    int row = mt * 16 + lr;
    int hrow = (row < 64) ? (h0 + row) : (448 + h0 + row);  // 512 + h0 + (row-64)
    gA[i] = wo + (size_t)hrow * kH + ks * 32 + lc * 8;
    int lrow = l0 + mt * 16 + lr;
    gB[i] = ytb + (size_t)lrow * kH + ks * 32 + lc * 8;
  }

  for (int k0 = 0; k0 < kH; k0 += 64) {
#pragma unroll
    for (int i = 0; i < 4; ++i) {
      int st = w * 4 + i;
      llds16(gA[i] + k0, &At[st][0][0]);
      llds16(gB[i] + k0, &Bt[st][0][0]);
    }
    __syncthreads();
#pragma unroll
    for (int ks = 0; ks < 2; ++ks) {
      f16x8 av[4], bv[4];
      av[0] = *(const f16x8*)At[(2 * wm + 0) * 2 + ks][lane];
      av[1] = *(const f16x8*)At[(2 * wm + 1) * 2 + ks][lane];
      av[2] = *(const f16x8*)At[(2 * wm + 4) * 2 + ks][lane];
      av[3] = *(const f16x8*)At[(2 * wm + 5) * 2 + ks][lane];
#pragma unroll
      for (int nt = 0; nt < 4; ++nt)
        bv[nt] = *(const f16x8*)Bt[(wn * 4 + nt) * 2 + ks][lane];
#pragma unroll
      for (int i = 0; i < 4; ++i)
#pragma unroll
        for (int nt = 0; nt < 4; ++nt)
          acc[i][nt] =
              __builtin_amdgcn_mfma_f32_16x16x32_f16(av[i], bv[nt], acc[i][nt], 0, 0, 0);
    }
    __syncthreads();
  }

  // epilogue: C/D layout col=lane&15, row=(lane>>4)*4+reg
  int col = lane & 15, q = lane >> 4;
  f16* ub = uout + (size_t)b * kH * kL;
#pragma unroll
  for (int i = 0; i < 2; ++i) {
#pragma unroll
    for (int reg = 0; reg < 4; ++reg) {
      int h = h0 + wm * 32 + i * 16 + q * 4 + reg;
      float b1 = bo[h], b2 = bo[h + kH];
#pragma unroll
      for (int nt = 0; nt < 4; ++nt) {
        float z1 = acc[i][nt][reg] + b1;
        float z2 = acc[i + 2][nt][reg] + b2;
        float sg = 1.f / (1.f + __expf(-z2));
        ub[(size_t)h * kL + l0 + wn * 64 + nt * 16 + col] = (f16)(z1 * sg);
      }
    }
  }
}

// ---------------------------------------------------------------------------
// K5: final projection via MFMA f16. out[b,p,h] = sum_l W[p,l] X[b,h,l] + b[p].
// Block 128 p-rows x 128 h-cols, K = L = 1024.
// ---------------------------------------------------------------------------
__global__ __launch_bounds__(256) void final_mfma_kernel(
    const f16* __restrict__ x,     // (B, H, L)
    const f16* __restrict__ wout,  // (P, L)
    const float* __restrict__ bout,
    float* __restrict__ outp) {  // (B, P, H) fp32
  __shared__ __align__(16) f16 At[16][64][8];
  __shared__ __align__(16) f16 Bt[16][64][8];
  int tid = threadIdx.x;
  int lane = tid & 63, w = tid >> 6;
  int wm = w >> 1, wn = w & 1;
  int lr = lane & 15, lc = lane >> 4;
  int b = blockIdx.z, p0 = blockIdx.y * 128, h0 = blockIdx.x * 128;
  const f16* xb = x + (size_t)b * kH * kL;

  f32x4 acc[4][4] = {};

  const f16* gA[4];
  const f16* gB[4];
#pragma unroll
  for (int i = 0; i < 4; ++i) {
    int st = w * 4 + i, mt = st >> 1, ks = st & 1;
    int prow = p0 + mt * 16 + lr;
    if (prow > kP - 1) prow = kP - 1;  // clamp; masked at store
    gA[i] = wout + (size_t)prow * kL + ks * 32 + lc * 8;
    int hrow = h0 + mt * 16 + lr;
    gB[i] = xb + (size_t)hrow * kL + ks * 32 + lc * 8;
  }

  for (int k0 = 0; k0 < kL; k0 += 64) {
#pragma unroll
    for (int i = 0; i < 4; ++i) {
      int st = w * 4 + i;
      llds16(gA[i] + k0, &At[st][0][0]);
      llds16(gB[i] + k0, &Bt[st][0][0]);
    }
    __syncthreads();
#pragma unroll
    for (int ks = 0; ks < 2; ++ks) {
      f16x8 av[4], bv[4];
#pragma unroll
      for (int i = 0; i < 4; ++i)
        av[i] = *(const f16x8*)At[(wm * 4 + i) * 2 + ks][lane];
#pragma unroll
      for (int nt = 0; nt < 4; ++nt)
        bv[nt] = *(const f16x8*)Bt[(wn * 4 + nt) * 2 + ks][lane];
#pragma unroll
      for (int i = 0; i < 4; ++i)
#pragma unroll
        for (int nt = 0; nt < 4; ++nt)
          acc[i][nt] =
              __builtin_amdgcn_mfma_f32_16x16x32_f16(av[i], bv[nt], acc[i][nt], 0, 0, 0);
    }
    __syncthreads();
  }

  int col = lane & 15, q = lane >> 4;
  float* ob = outp + (size_t)b * kP * kH;
#pragma unroll
  for (int i = 0; i < 4; ++i) {
#pragma unroll
    for (int reg = 0; reg < 4; ++reg) {
      int p = p0 + wm * 64 + i * 16 + q * 4 + reg;
      if (p < kP) {
        float bv2 = bout[p];
#pragma unroll
        for (int nt = 0; nt < 4; ++nt)
          ob[(size_t)p * kH + h0 + wn * 64 + nt * 16 + col] = acc[i][nt][reg] + bv2;
      }
    }
  }
}

}  // namespace

extern "C" void kernel_launch(void* const* d_in, const int* in_sizes, int n_in,
                              void* d_out, int out_size, void* d_ws, size_t ws_size,
                              hipStream_t stream) {
  const float* x_enc  = (const float*)d_in[0];
  const float* log_dt = (const float*)d_in[4];
  const float* A_re   = (const float*)d_in[5];
  const float* A_im   = (const float*)d_in[6];
  const float* C_re   = (const float*)d_in[7];
  const float* C_im   = (const float*)d_in[8];
  const float* Dskip  = (const float*)d_in[9];
  const float* Wo     = (const float*)d_in[10];
  const float* bo     = (const float*)d_in[11];
  const float* W_out  = (const float*)d_in[12];
  const float* b_out  = (const float*)d_in[13];
  float* out = (float*)d_out;

  char* wsb = (char*)d_ws;
  f16* u16    = (f16*)(wsb);                  // 32 MB  (B,H,L)
  f16* yt16   = (f16*)(wsb + 33554432);       // 32 MB  (B,L,H)
  f16* wo16   = (f16*)(wsb + 67108864);       // 3 MB   (NL,2H,H)
  f16* wout16 = (f16*)(wsb + 70254592);       // 672 KB (P,L)
  float* prr  = (float*)(wsb + 70942720);
  float* pri  = prr + kNL * kH * kNS;
  float* pcr  = pri + kNL * kH * kNS;
  float* pci  = pcr + kNL * kH * kNS;

  const int nwo = kNL * 2 * kH * kH;  // 1,572,864
  const int nwp = kP * kL;            // 344,064
  f32_to_f16_kernel<<<(nwo + 255) / 256, 256, 0, stream>>>(Wo, wo16, nwo);
  f32_to_f16_kernel<<<(nwp + 255) / 256, 256, 0, stream>>>(W_out, wout16, nwp);

  ssm_params_kernel<<<(kNL * kH * kNS + 255) / 256, 256, 0, stream>>>(
      log_dt, A_re, A_im, C_re, C_im, prr, pri, pcr, pci);

  transpose_kernel<<<dim3(kL / 32, kH / 32, kB), dim3(32, 8), 0, stream>>>(x_enc, u16);

  for (int layer = 0; layer < kNL; layer++) {
    s4_scan_kernel<<<kB * kH / 32, 256, 0, stream>>>(u16, yt16, prr, pri, pcr, pci,
                                                     Dskip, layer);
    glu_mfma_kernel<<<dim3(kL / 128, kH / 64, kB), 256, 0, stream>>>(
        yt16, wo16 + (size_t)layer * 2 * kH * kH, bo + (size_t)layer * 2 * kH, u16);
  }

  final_mfma_kernel<<<dim3(kH / 128, 3, kB), 256, 0, stream>>>(u16, wout16, b_out, out);
}